// Round 9
// baseline (108.654 us; speedup 1.0000x reference)
//
#include <hip/hip_runtime.h>
#include <hip/hip_fp16.h>

#define D 128
#define C 5

typedef _Float16 half8 __attribute__((ext_vector_type(8)));
typedef _Float16 half4 __attribute__((ext_vector_type(4)));
typedef float f32x4 __attribute__((ext_vector_type(4)));
typedef float f32x8 __attribute__((ext_vector_type(8)));

// ---------------------------------------------------------------------------
// Kernel 0: W1 (128x256 fp32) -> W1h fp16 (same layout);
//           W2 (5x128 fp32)   -> W2h fp16 [16][128] zero-padded.
// ---------------------------------------------------------------------------
__global__ __launch_bounds__(256) void convert_weights(
    const float* __restrict__ W1, const float* __restrict__ W2,
    _Float16* __restrict__ W1h, _Float16* __restrict__ W2h)
{
    int idx = blockIdx.x * 256 + threadIdx.x;
    if (idx < D * 2 * D) {
        W1h[idx] = (_Float16)W1[idx];
    } else {
        int j = idx - D * 2 * D;
        if (j < 16 * D) {
            int r = j >> 7;
            int k = j & 127;
            W2h[j] = (_Float16)((r < C) ? W2[r * D + k] : 0.f);
        }
    }
}

// ---------------------------------------------------------------------------
// Kernel 1: U/V precompute via MFMA. R9 = R7 config (128 rows/block, fp16
// W1h staging, 32 KB swizzled LDS) + R8's swapped-operand MFMA so each lane
// holds one feature row x 4 consecutive cols -> packed 8-B stores
// (16 store instrs/thread-loop vs 64 scalar 2-B in R7).
// C layout (swapped): row = l&15 (+rt*16), cols = ct*16 + (l>>4)*4 + j.
// ---------------------------------------------------------------------------
__global__ __launch_bounds__(256) void precompute_uv(
    const float* __restrict__ ufeat, const float* __restrict__ ifeat,
    const _Float16* __restrict__ W1h, _Float16* __restrict__ U,
    _Float16* __restrict__ V, int n_users, int n_movies, int groupsU)
{
    __shared__ _Float16 ldsB[128 * 128];   // 32 KB, swizzled fp16 W1-half
    char* lb = (char*)ldsB;

    int gid = blockIdx.x;
    const float* feat;
    _Float16* out;
    int off, base_row, nrows;
    if (gid < groupsU) {
        feat = ufeat; out = U; off = 0;
        base_row = gid * 128; nrows = n_users;
    } else {
        feat = ifeat; out = V; off = D;
        base_row = (gid - groupsU) * 128; nrows = n_movies;
    }

    int tid = threadIdx.x;
    int w = tid >> 6;
    int l = tid & 63;
    int row16 = l & 15;
    int kg = l >> 4;

    // --- Feature fragments first (HBM loads in flight during LDS staging).
    int rbase = base_row + w * 32;
    half8 afrag[2][4];   // [rowtile][kb]
    #pragma unroll
    for (int t = 0; t < 2; ++t) {
        int ra = rbase + t * 16 + row16;
        int rc = (ra < nrows) ? ra : (nrows - 1);
        const float* fp = feat + (size_t)rc * D + kg * 8;
        #pragma unroll
        for (int kb = 0; kb < 4; ++kb) {
            f32x8 f = *reinterpret_cast<const f32x8*>(&fp[kb * 32]);
            afrag[t][kb] = __builtin_convertvector(f, half8);
        }
    }

    // --- Stage W1h half into LDS (swizzled). 32 KB / 256 thr = 8 x 16 B.
    {
        const char* wbase = (const char*)W1h + off * 2;
        #pragma unroll
        for (int i = 0; i < 8; ++i) {
            int lin = (tid + i * 256) * 16;
            int col = lin >> 8;
            int within = lin & 255;
            const char* srcp = wbase + (size_t)col * 512 + within;
            int dstb = lin ^ ((col & 7) << 4);
            *reinterpret_cast<uint4*>(lb + dstb) =
                *reinterpret_cast<const uint4*>(srcp);
        }
    }
    __syncthreads();

    // --- Main loop: 8 col-tiles x 2 row-tiles, 4 MFMA each (K=128).
    // Swapped operands: W-frag as A, F-frag as B -> packed-row D layout.
    #pragma unroll 2
    for (int ct = 0; ct < 8; ++ct) {
        int c = ct * 16 + row16;           // W1 row (= output col) this lane
        int sw = (c & 7) << 4;
        int bb = c * 256 + kg * 16;
        half8 w0 = *reinterpret_cast<const half8*>(lb + ((bb +   0) ^ sw));
        half8 w1 = *reinterpret_cast<const half8*>(lb + ((bb +  64) ^ sw));
        half8 w2 = *reinterpret_cast<const half8*>(lb + ((bb + 128) ^ sw));
        half8 w3 = *reinterpret_cast<const half8*>(lb + ((bb + 192) ^ sw));

        #pragma unroll
        for (int rt = 0; rt < 2; ++rt) {
            f32x4 acc = {0.f, 0.f, 0.f, 0.f};
            acc = __builtin_amdgcn_mfma_f32_16x16x32_f16(w0, afrag[rt][0], acc, 0, 0, 0);
            acc = __builtin_amdgcn_mfma_f32_16x16x32_f16(w1, afrag[rt][1], acc, 0, 0, 0);
            acc = __builtin_amdgcn_mfma_f32_16x16x32_f16(w2, afrag[rt][2], acc, 0, 0, 0);
            acc = __builtin_amdgcn_mfma_f32_16x16x32_f16(w3, afrag[rt][3], acc, 0, 0, 0);

            int r = rbase + rt * 16 + row16;
            if (r < nrows) {
                half4 hv = __builtin_convertvector(acc, half4);
                *reinterpret_cast<half4*>(&out[(size_t)r * D + ct * 16 + kg * 4]) = hv;
            }
        }
    }
}

// ---------------------------------------------------------------------------
// Kernel 2 (R6 verbatim — at structural gather floor):
// score = relu(U[src]+V[dst]) @ W2.T via MFMA 16x16x32 f16, 64 edges/wave,
// B-frags from fp16 W2h.
// ---------------------------------------------------------------------------
__global__ __launch_bounds__(256) void edge_mlp(
    const _Float16* __restrict__ U, const _Float16* __restrict__ V,
    const _Float16* __restrict__ W2h,
    const int* __restrict__ src, const int* __restrict__ dst,
    float* __restrict__ out, int E)
{
    int tid = threadIdx.x;
    int w = tid >> 6;
    int l = tid & 63;
    int base = blockIdx.x * 256 + w * 64;
    int row16 = l & 15;
    int kg = l >> 4;

    half8 bfrag[4];
    #pragma unroll
    for (int kb = 0; kb < 4; ++kb)
        bfrag[kb] = *reinterpret_cast<const half8*>(&W2h[row16 * D + kb * 32 + kg * 8]);

    int i64 = base + l;
    int ic = (i64 < E) ? i64 : (E - 1);
    int sv = src[ic];
    int dv = dst[ic];

    const _Float16* up[4];
    const _Float16* vp[4];
    #pragma unroll
    for (int g = 0; g < 4; ++g) {
        int sg_ = __shfl(sv, g * 16 + row16);
        int dg_ = __shfl(dv, g * 16 + row16);
        up[g] = &U[(size_t)sg_ * D + kg * 8];
        vp[g] = &V[(size_t)dg_ * D + kg * 8];
    }

    f32x4 acc[4];
    #pragma unroll
    for (int g = 0; g < 4; ++g) acc[g] = (f32x4){0.f, 0.f, 0.f, 0.f};

    #pragma unroll
    for (int kb = 0; kb < 4; ++kb) {
        half8 au0 = *reinterpret_cast<const half8*>(&up[0][kb * 32]);
        half8 av0 = *reinterpret_cast<const half8*>(&vp[0][kb * 32]);
        half8 au1 = *reinterpret_cast<const half8*>(&up[1][kb * 32]);
        half8 av1 = *reinterpret_cast<const half8*>(&vp[1][kb * 32]);
        half8 au2 = *reinterpret_cast<const half8*>(&up[2][kb * 32]);
        half8 av2 = *reinterpret_cast<const half8*>(&vp[2][kb * 32]);
        half8 au3 = *reinterpret_cast<const half8*>(&up[3][kb * 32]);
        half8 av3 = *reinterpret_cast<const half8*>(&vp[3][kb * 32]);
        half8 h0 = __builtin_elementwise_max(au0 + av0, (half8)(_Float16)0.f);
        half8 h1 = __builtin_elementwise_max(au1 + av1, (half8)(_Float16)0.f);
        half8 h2 = __builtin_elementwise_max(au2 + av2, (half8)(_Float16)0.f);
        half8 h3 = __builtin_elementwise_max(au3 + av3, (half8)(_Float16)0.f);
        acc[0] = __builtin_amdgcn_mfma_f32_16x16x32_f16(h0, bfrag[kb], acc[0], 0, 0, 0);
        acc[1] = __builtin_amdgcn_mfma_f32_16x16x32_f16(h1, bfrag[kb], acc[1], 0, 0, 0);
        acc[2] = __builtin_amdgcn_mfma_f32_16x16x32_f16(h2, bfrag[kb], acc[2], 0, 0, 0);
        acc[3] = __builtin_amdgcn_mfma_f32_16x16x32_f16(h3, bfrag[kb], acc[3], 0, 0, 0);
    }

    int col = row16;
    if (col < C) {
        #pragma unroll
        for (int g = 0; g < 4; ++g) {
            #pragma unroll
            for (int j = 0; j < 4; ++j) {
                int er = base + g * 16 + kg * 4 + j;
                if (er < E) out[(size_t)er * C + col] = acc[g][j];
            }
        }
    }
}

extern "C" void kernel_launch(void* const* d_in, const int* in_sizes, int n_in,
                              void* d_out, int out_size, void* d_ws, size_t ws_size,
                              hipStream_t stream) {
    (void)n_in; (void)out_size; (void)ws_size;
    const float* ufeat = (const float*)d_in[0];
    const float* ifeat = (const float*)d_in[1];
    const float* W1    = (const float*)d_in[2];
    const float* W2    = (const float*)d_in[3];
    const int*   src   = (const int*)d_in[4];
    const int*   dst   = (const int*)d_in[5];

    int n_users  = in_sizes[0] / D;
    int n_movies = in_sizes[1] / D;
    int E        = in_sizes[4];

    float* out = (float*)d_out;
    _Float16* Ubuf = (_Float16*)d_ws;                    // n_users*128 fp16
    _Float16* Vbuf = Ubuf + (size_t)n_users * D;         // n_movies*128 fp16
    _Float16* W2h  = Vbuf + (size_t)n_movies * D;        // 16*128 fp16
    _Float16* W1h  = W2h + 16 * D;                       // 128*256 fp16

    convert_weights<<<(D * 2 * D + 16 * D + 255) / 256, 256, 0, stream>>>(
        W1, W2, W1h, W2h);

    int groupsU = (n_users + 127) / 128;
    int groupsV = (n_movies + 127) / 128;
    precompute_uv<<<groupsU + groupsV, 256, 0, stream>>>(
        ufeat, ifeat, W1h, Ubuf, Vbuf, n_users, n_movies, groupsU);

    int eblocks = (E + 255) / 256;
    edge_mlp<<<eblocks, 256, 0, stream>>>(Ubuf, Vbuf, W2h, src, dst, out, E);
}

// Round 10
// 104.693 us; speedup vs baseline: 1.0378x; 1.0378x over previous
//
#include <hip/hip_runtime.h>
#include <hip/hip_fp16.h>

#define D 128
#define C 5

typedef _Float16 half8 __attribute__((ext_vector_type(8)));
typedef float f32x4 __attribute__((ext_vector_type(4)));
typedef float f32x8 __attribute__((ext_vector_type(8)));

// ---------------------------------------------------------------------------
// Kernel 0: W1 (128x256 fp32) -> W1h fp16 (same layout);
//           W2 (5x128 fp32)   -> W2h fp16 [16][128] zero-padded.
// ---------------------------------------------------------------------------
__global__ __launch_bounds__(256) void convert_weights(
    const float* __restrict__ W1, const float* __restrict__ W2,
    _Float16* __restrict__ W1h, _Float16* __restrict__ W2h)
{
    int idx = blockIdx.x * 256 + threadIdx.x;
    if (idx < D * 2 * D) {
        W1h[idx] = (_Float16)W1[idx];
    } else {
        int j = idx - D * 2 * D;
        if (j < 16 * D) {
            int r = j >> 7;
            int k = j & 127;
            W2h[j] = (_Float16)((r < C) ? W2[r * D + k] : 0.f);
        }
    }
}

// ---------------------------------------------------------------------------
// Kernel 1 (R7 config — best measured): U/V precompute via MFMA.
// 128 rows/block (32 rows/wave, 2 A-tiles x 4 kb in regs, 2 MFMA chains),
// 1173 blocks (~4.6/CU). A-fragment global loads issued BEFORE LDS staging
// so HBM latency overlaps stage+sync.
// LDS: W1 half fp16, 32 KB, XOR-swizzled (byte ^= (col&7)<<4).
// C layout: col = l&15, row = (l>>4)*4 + j. Scalar 2-B stores are
// well-coalesced per wave (4 rows x 32 B runs) — measured faster than the
// swapped-operand packed-store variant (R8/R9).
// ---------------------------------------------------------------------------
__global__ __launch_bounds__(256) void precompute_uv(
    const float* __restrict__ ufeat, const float* __restrict__ ifeat,
    const _Float16* __restrict__ W1h, _Float16* __restrict__ U,
    _Float16* __restrict__ V, int n_users, int n_movies, int groupsU)
{
    __shared__ _Float16 ldsB[128 * 128];   // 32 KB, swizzled layout
    char* lb = (char*)ldsB;

    int gid = blockIdx.x;
    const float* feat;
    _Float16* out;
    int off, base_row, nrows;
    if (gid < groupsU) {
        feat = ufeat; out = U; off = 0;
        base_row = gid * 128; nrows = n_users;
    } else {
        feat = ifeat; out = V; off = D;
        base_row = (gid - groupsU) * 128; nrows = n_movies;
    }

    int tid = threadIdx.x;
    int w = tid >> 6;
    int l = tid & 63;
    int row16 = l & 15;
    int kg = l >> 4;

    // --- A fragments first (HBM loads in flight during LDS staging).
    int rbase = base_row + w * 32;
    half8 afrag[2][4];   // [tile][kb]
    #pragma unroll
    for (int t = 0; t < 2; ++t) {
        int ra = rbase + t * 16 + row16;
        int rc = (ra < nrows) ? ra : (nrows - 1);
        const float* fp = feat + (size_t)rc * D + kg * 8;
        #pragma unroll
        for (int kb = 0; kb < 4; ++kb) {
            f32x8 f = *reinterpret_cast<const f32x8*>(&fp[kb * 32]);
            afrag[t][kb] = __builtin_convertvector(f, half8);
        }
    }

    // --- Stage W1 half into LDS (swizzled). 32 KB / 256 thr = 8 x 16 B.
    {
        const char* wbase = (const char*)W1h + off * 2;
        #pragma unroll
        for (int i = 0; i < 8; ++i) {
            int lin = (tid + i * 256) * 16;
            int col = lin >> 8;
            int within = lin & 255;
            const char* srcp = wbase + (size_t)col * 512 + within;
            int dstb = lin ^ ((col & 7) << 4);
            *reinterpret_cast<uint4*>(lb + dstb) =
                *reinterpret_cast<const uint4*>(srcp);
        }
    }
    __syncthreads();

    // --- Main loop over column groups.
    #pragma unroll 2
    for (int jt = 0; jt < 8; ++jt) {
        int col = jt * 16 + row16;
        int sw = (col & 7) << 4;
        int bb = col * 256 + kg * 16;
        half8 b0 = *reinterpret_cast<const half8*>(lb + ((bb +   0) ^ sw));
        half8 b1 = *reinterpret_cast<const half8*>(lb + ((bb +  64) ^ sw));
        half8 b2 = *reinterpret_cast<const half8*>(lb + ((bb + 128) ^ sw));
        half8 b3 = *reinterpret_cast<const half8*>(lb + ((bb + 192) ^ sw));

        f32x4 acc0 = {0.f, 0.f, 0.f, 0.f};
        f32x4 acc1 = {0.f, 0.f, 0.f, 0.f};
        acc0 = __builtin_amdgcn_mfma_f32_16x16x32_f16(afrag[0][0], b0, acc0, 0, 0, 0);
        acc1 = __builtin_amdgcn_mfma_f32_16x16x32_f16(afrag[1][0], b0, acc1, 0, 0, 0);
        acc0 = __builtin_amdgcn_mfma_f32_16x16x32_f16(afrag[0][1], b1, acc0, 0, 0, 0);
        acc1 = __builtin_amdgcn_mfma_f32_16x16x32_f16(afrag[1][1], b1, acc1, 0, 0, 0);
        acc0 = __builtin_amdgcn_mfma_f32_16x16x32_f16(afrag[0][2], b2, acc0, 0, 0, 0);
        acc1 = __builtin_amdgcn_mfma_f32_16x16x32_f16(afrag[1][2], b2, acc1, 0, 0, 0);
        acc0 = __builtin_amdgcn_mfma_f32_16x16x32_f16(afrag[0][3], b3, acc0, 0, 0, 0);
        acc1 = __builtin_amdgcn_mfma_f32_16x16x32_f16(afrag[1][3], b3, acc1, 0, 0, 0);

        int r0 = rbase + kg * 4;
        #pragma unroll
        for (int j = 0; j < 4; ++j) {
            int r = r0 + j;
            if (r +  0 < nrows) out[(size_t)(r +  0) * D + col] = (_Float16)acc0[j];
            if (r + 16 < nrows) out[(size_t)(r + 16) * D + col] = (_Float16)acc1[j];
        }
    }
}

// ---------------------------------------------------------------------------
// Kernel 2 (R6 verbatim — at structural gather floor):
// score = relu(U[src]+V[dst]) @ W2.T via MFMA 16x16x32 f16, 64 edges/wave,
// B-frags from fp16 W2h.
// ---------------------------------------------------------------------------
__global__ __launch_bounds__(256) void edge_mlp(
    const _Float16* __restrict__ U, const _Float16* __restrict__ V,
    const _Float16* __restrict__ W2h,
    const int* __restrict__ src, const int* __restrict__ dst,
    float* __restrict__ out, int E)
{
    int tid = threadIdx.x;
    int w = tid >> 6;
    int l = tid & 63;
    int base = blockIdx.x * 256 + w * 64;
    int row16 = l & 15;
    int kg = l >> 4;

    half8 bfrag[4];
    #pragma unroll
    for (int kb = 0; kb < 4; ++kb)
        bfrag[kb] = *reinterpret_cast<const half8*>(&W2h[row16 * D + kb * 32 + kg * 8]);

    int i64 = base + l;
    int ic = (i64 < E) ? i64 : (E - 1);
    int sv = src[ic];
    int dv = dst[ic];

    const _Float16* up[4];
    const _Float16* vp[4];
    #pragma unroll
    for (int g = 0; g < 4; ++g) {
        int sg_ = __shfl(sv, g * 16 + row16);
        int dg_ = __shfl(dv, g * 16 + row16);
        up[g] = &U[(size_t)sg_ * D + kg * 8];
        vp[g] = &V[(size_t)dg_ * D + kg * 8];
    }

    f32x4 acc[4];
    #pragma unroll
    for (int g = 0; g < 4; ++g) acc[g] = (f32x4){0.f, 0.f, 0.f, 0.f};

    #pragma unroll
    for (int kb = 0; kb < 4; ++kb) {
        half8 au0 = *reinterpret_cast<const half8*>(&up[0][kb * 32]);
        half8 av0 = *reinterpret_cast<const half8*>(&vp[0][kb * 32]);
        half8 au1 = *reinterpret_cast<const half8*>(&up[1][kb * 32]);
        half8 av1 = *reinterpret_cast<const half8*>(&vp[1][kb * 32]);
        half8 au2 = *reinterpret_cast<const half8*>(&up[2][kb * 32]);
        half8 av2 = *reinterpret_cast<const half8*>(&vp[2][kb * 32]);
        half8 au3 = *reinterpret_cast<const half8*>(&up[3][kb * 32]);
        half8 av3 = *reinterpret_cast<const half8*>(&vp[3][kb * 32]);
        half8 h0 = __builtin_elementwise_max(au0 + av0, (half8)(_Float16)0.f);
        half8 h1 = __builtin_elementwise_max(au1 + av1, (half8)(_Float16)0.f);
        half8 h2 = __builtin_elementwise_max(au2 + av2, (half8)(_Float16)0.f);
        half8 h3 = __builtin_elementwise_max(au3 + av3, (half8)(_Float16)0.f);
        acc[0] = __builtin_amdgcn_mfma_f32_16x16x32_f16(h0, bfrag[kb], acc[0], 0, 0, 0);
        acc[1] = __builtin_amdgcn_mfma_f32_16x16x32_f16(h1, bfrag[kb], acc[1], 0, 0, 0);
        acc[2] = __builtin_amdgcn_mfma_f32_16x16x32_f16(h2, bfrag[kb], acc[2], 0, 0, 0);
        acc[3] = __builtin_amdgcn_mfma_f32_16x16x32_f16(h3, bfrag[kb], acc[3], 0, 0, 0);
    }

    int col = row16;
    if (col < C) {
        #pragma unroll
        for (int g = 0; g < 4; ++g) {
            #pragma unroll
            for (int j = 0; j < 4; ++j) {
                int er = base + g * 16 + kg * 4 + j;
                if (er < E) out[(size_t)er * C + col] = acc[g][j];
            }
        }
    }
}

extern "C" void kernel_launch(void* const* d_in, const int* in_sizes, int n_in,
                              void* d_out, int out_size, void* d_ws, size_t ws_size,
                              hipStream_t stream) {
    (void)n_in; (void)out_size; (void)ws_size;
    const float* ufeat = (const float*)d_in[0];
    const float* ifeat = (const float*)d_in[1];
    const float* W1    = (const float*)d_in[2];
    const float* W2    = (const float*)d_in[3];
    const int*   src   = (const int*)d_in[4];
    const int*   dst   = (const int*)d_in[5];

    int n_users  = in_sizes[0] / D;
    int n_movies = in_sizes[1] / D;
    int E        = in_sizes[4];

    float* out = (float*)d_out;
    _Float16* Ubuf = (_Float16*)d_ws;                    // n_users*128 fp16
    _Float16* Vbuf = Ubuf + (size_t)n_users * D;         // n_movies*128 fp16
    _Float16* W2h  = Vbuf + (size_t)n_movies * D;        // 16*128 fp16
    _Float16* W1h  = W2h + 16 * D;                       // 128*256 fp16

    convert_weights<<<(D * 2 * D + 16 * D + 255) / 256, 256, 0, stream>>>(
        W1, W2, W1h, W2h);

    int groupsU = (n_users + 127) / 128;
    int groupsV = (n_movies + 127) / 128;
    precompute_uv<<<groupsU + groupsV, 256, 0, stream>>>(
        ufeat, ifeat, W1h, Ubuf, Vbuf, n_users, n_movies, groupsU);

    int eblocks = (E + 255) / 256;
    edge_mlp<<<eblocks, 256, 0, stream>>>(Ubuf, Vbuf, W2h, src, dst, out, E);
}